// Round 12
// baseline (201.303 us; speedup 1.0000x reference)
//
#include <hip/hip_runtime.h>
#include <hip/hip_bf16.h>

// Problem constants (fixed by the reference).
#define BB 32
#define SS 256
#define DD 256
#define UU 256
#define LL 16
#define DEG 16
#define NN (BB * SS)   // 8192 nodes
#define EE (NN * DEG)  // 131072 edges per branch
#define NSLICE 33      // slice 0 = self-loop, 1..16 = in labels, 17..32 = out labels
#define TMR 128        // GEMM row tile
#define TNC 128        // GEMM col tile (U half)
#define BK 64          // GEMM k step
#define NTILES (DD / BK)  // 4 k-tiles (K = 256)
#define EST 136        // epilogue LDS row stride (elems); 64 rows/half-tile

using short8 = __attribute__((ext_vector_type(8))) short;  // 8 bf16 (4 VGPRs)
using f32x4  = __attribute__((ext_vector_type(4))) float;  // MFMA accumulator

// async global->LDS, 16B per lane, LDS dest = wave-uniform base + lane*16
#define GLDS(g, l)                                                        \
  __builtin_amdgcn_global_load_lds(                                       \
      (const __attribute__((address_space(1))) void*)(g),                 \
      (__attribute__((address_space(3))) void*)(l), 16, 0, 0)

__device__ __forceinline__ float bf2f(unsigned short v) {
  union { unsigned u; float f; } t;
  t.u = ((unsigned)v) << 16;
  return t.f;
}
__device__ __forceinline__ unsigned short f2bf(float f) {
  __hip_bfloat16 h = __float2bfloat16(f);
  return *(unsigned short*)&h;
}
__device__ __forceinline__ float sigm(float x) {
  return 1.f / (1.f + __expf(-x));
}

// ---------------------------------------------------------------------------
// K1: blocks [0,NN): prep (x cast to bf16 + 3 gate dots).
// blocks [NN, NN+NSLICE*64): weight transpose Vt[z][u][d] = V_z[d][u] (bf16).
// Verbatim R11 (passing). Bias applied per-edge in k_agg.
// ---------------------------------------------------------------------------
__global__ __launch_bounds__(256) void k_pre(
    const float* __restrict__ src, const float* __restrict__ gin,
    const float* __restrict__ gout, const float* __restrict__ gloop,
    const float* __restrict__ Vin, const float* __restrict__ Vout,
    const float* __restrict__ Wself,
    __hip_bfloat16* __restrict__ x_bf, float* __restrict__ xg_in,
    float* __restrict__ xg_out, float* __restrict__ xg_loop,
    __hip_bfloat16* __restrict__ Vt) {
  int bid = blockIdx.x;
  if (bid < NN) {
    int n = bid;
    int b = n / SS, s = n % SS;
    int d = threadIdx.x;
    float v = src[(size_t)(s * BB + b) * DD + d];
    x_bf[(size_t)n * DD + d] = __float2bfloat16(v);
    float p0 = v * gin[d], p1 = v * gout[d], p2 = v * gloop[d];
#pragma unroll
    for (int o = 32; o > 0; o >>= 1) {
      p0 += __shfl_down(p0, o);
      p1 += __shfl_down(p1, o);
      p2 += __shfl_down(p2, o);
    }
    __shared__ float r0[4], r1[4], r2[4];
    int w = threadIdx.x >> 6, lane = threadIdx.x & 63;
    if (lane == 0) { r0[w] = p0; r1[w] = p1; r2[w] = p2; }
    __syncthreads();
    if (threadIdx.x == 0) {
      xg_in[n]   = r0[0] + r0[1] + r0[2] + r0[3];
      xg_out[n]  = r1[0] + r1[1] + r1[2] + r1[3];
      xg_loop[n] = r2[0] + r2[1] + r2[2] + r2[3];
    }
    return;
  }
  int t = bid - NN;
  int z = t >> 6;                 // 0..NSLICE-1
  int rem = t & 63;
  int bx = rem & 7, by = rem >> 3;
  int tid = threadIdx.x;
  int tx = tid & 31, ty = tid >> 5;
  __shared__ float tbuf[32][33];
  const float* srcM = (z == 0) ? Wself
                    : (z <= LL ? Vin  + (size_t)(z - 1)      * DD * UU
                               : Vout + (size_t)(z - 1 - LL) * DD * UU);
  int u0 = bx * 32, d0 = by * 32;
#pragma unroll
  for (int i = 0; i < 4; i++) {
    int dr = ty + i * 8;
    tbuf[dr][tx] = srcM[(size_t)(d0 + dr) * UU + u0 + tx];
  }
  __syncthreads();
#pragma unroll
  for (int i = 0; i < 4; i++) {
    int ur = ty + i * 8;
    Vt[((size_t)z * UU + u0 + ur) * DD + d0 + tx] = __float2bfloat16(tbuf[tx][ur]);
  }
}

// ---------------------------------------------------------------------------
// K2: H[z] = x @ V_z, 128x128 tiles, 4 waves, single-buffered 32 KB LDS.
// R12 change: 3 -> 5 blocks/CU (launch_bounds(256,5); VGPR 68 <= 102 cap,
// LDS 5x32 = 160 KiB exact) — R11 showed write-burst overlap is the limiter
// and resources allow 5 resident blocks. Everything else verbatim R11
// (T2 swizzle both sides, GLDS staging, unswapped C/D, LDS-transpose
// epilogue at EST=136). grid (128, 33): blockIdx.x = rowblk*2 + colhalf.
// ---------------------------------------------------------------------------
__global__ __launch_bounds__(256, 5) void k_gemm(
    const __hip_bfloat16* __restrict__ A, const __hip_bfloat16* __restrict__ Bt,
    __hip_bfloat16* __restrict__ H) {
  __shared__ __align__(16) __hip_bfloat16 smem[2 * TMR * BK];  // As | Bs, 32 KB

  const int tid = threadIdx.x;
  const int w = tid >> 6, lane = tid & 63;
  const int wm = w >> 1, wn = w & 1;           // wave grid 2x2
  const int lrow = lane & 15, quad = lane >> 4;

  const int z = blockIdx.y;
  const int bx = blockIdx.x >> 1;              // row block 0..63
  const int ch = blockIdx.x & 1;               // col half 0..1
  const int row0 = bx * TMR;
  const int col0 = ch * TNC;

  // Staging: round r covers rows [r*32, r*32+32); thread tid writes LDS
  // bytes r*4096 + tid*16 (linear dest). Global source pre-swizzled (T2):
  // chunk (tid&7) ^ (row&7); round rows are 32-aligned so key = arow&7.
  const int arow = tid >> 3;                       // 0..31 row within round
  const int scol = ((tid & 7) ^ (arow & 7)) << 3;  // swizzled k-elem offset
  const __hip_bfloat16* srcA = A + (size_t)(row0 + arow) * DD + scol;
  const __hip_bfloat16* srcB = Bt + ((size_t)z * UU + col0 + arow) * DD + scol;

  __hip_bfloat16* As = smem;
  __hip_bfloat16* Bs = smem + TMR * BK;

  // ds_read swizzled k-slot offsets (elements) for the two k-halves;
  // read rows are 16-aligned + lrow so key = lrow&7.
  const int sc0 = ((quad ^ (lrow & 7)) << 3);
  const int sc1 = (((4 + quad) ^ (lrow & 7)) << 3);

  f32x4 acc[4][4] = {};

  for (int t = 0; t < NTILES; ++t) {
    const int k0 = t * BK;
#pragma unroll
    for (int r = 0; r < 4; ++r)
      GLDS(srcA + (size_t)(r * 32) * DD + k0, &As[r * 2048 + (w << 9)]);
#pragma unroll
    for (int r = 0; r < 4; ++r)
      GLDS(srcB + (size_t)(r * 32) * DD + k0, &Bs[r * 2048 + (w << 9)]);
    __syncthreads();   // compiler emits vmcnt(0)+lgkmcnt(0) before barrier

    short8 af[4][2];
#pragma unroll
    for (int i = 0; i < 4; ++i) {
      int ro = (wm * 64 + i * 16 + lrow) * BK;
      af[i][0] = *(const short8*)&As[ro + sc0];
      af[i][1] = *(const short8*)&As[ro + sc1];
    }
#pragma unroll
    for (int j = 0; j < 4; ++j) {
      int ro = (wn * 64 + j * 16 + lrow) * BK;
      short8 b0 = *(const short8*)&Bs[ro + sc0];
      short8 b1 = *(const short8*)&Bs[ro + sc1];
#pragma unroll
      for (int i = 0; i < 4; ++i) {
        acc[i][j] = __builtin_amdgcn_mfma_f32_16x16x32_bf16(
            af[i][0], b0, acc[i][j], 0, 0, 0);
        acc[i][j] = __builtin_amdgcn_mfma_f32_16x16x32_bf16(
            af[i][1], b1, acc[i][j], 0, 0, 0);
      }
    }
    __syncthreads();   // reads done before next tile's staging overwrites
  }

  // ---- Epilogue: two 64-row half-tiles through LDS, coalesced stores ----
  // Wave wm owns tile rows [wm*64, wm*64+64) = half h == wm.
  unsigned short* ep = (unsigned short*)smem;     // needs 64*136=8704 elems
  unsigned short* hp = (unsigned short*)H;
#pragma unroll
  for (int h = 0; h < 2; ++h) {
    if (wm == h) {
      // unswapped C/D layout (R8/R10/R11-verified): col=lane&15 -> u,
      // quad*4+r -> n within the 16x16 fragment.
#pragma unroll
      for (int i = 0; i < 4; ++i)
#pragma unroll
        for (int j = 0; j < 4; ++j) {
          int col = wn * 64 + j * 16 + lrow;     // u in [0,128)
          int rowl = i * 16 + quad * 4;          // row within half [0,64)
#pragma unroll
          for (int r = 0; r < 4; ++r)
            ep[(rowl + r) * EST + col] = f2bf(acc[i][j][r]);
        }
    }
    __syncthreads();
    // 64 rows x 16 chunks of 16 B = 1024 chunks; 256 thr x 4 iters
#pragma unroll
    for (int it = 0; it < 4; ++it) {
      int idx = it * 256 + tid;
      int rr = idx >> 4;                 // 0..63
      int cc = (idx & 15) << 3;          // u chunk (elems)
      short8 v = *(const short8*)&ep[rr * EST + cc];
      *(short8*)&hp[((size_t)z * NN + row0 + h * 64 + rr) * UU + col0 + cc] = v;
    }
    __syncthreads();   // copy done before next half overwrites ep
  }
}

// ---------------------------------------------------------------------------
// K3: aggregation in U-space, fused with bias/relu/sent_mask/transpose.
// Verbatim R2/R10/R11 (passing). One wave per dst node; per-edge gather is
// a wave-uniform 512 B row of H.
// ---------------------------------------------------------------------------
__global__ __launch_bounds__(64) void k_agg(
    const __hip_bfloat16* __restrict__ H,
    const float* __restrict__ xg_in, const float* __restrict__ xg_out,
    const float* __restrict__ xg_loop,
    const float* __restrict__ b_in, const float* __restrict__ b_out,
    const float* __restrict__ b_ing, const float* __restrict__ b_outg,
    const int* __restrict__ arc_in, const int* __restrict__ arc_out,
    const int* __restrict__ lab_in, const int* __restrict__ lab_out,
    const float* __restrict__ mask_in, const float* __restrict__ mask_out,
    const float* __restrict__ mask_loop, const float* __restrict__ sent,
    float* __restrict__ out) {
  __shared__ int u_sl[32], u_src[32];
  __shared__ float u_w[32];
  int n = blockIdx.x, tid = threadIdx.x;
  if (tid < 32) {
    int br = tid >> 4, k = tid & 15;
    int e = n * DEG + k;
    const int* a = br ? arc_out : arc_in;
    int l = (br ? lab_out : lab_in)[e];
    int srcn = a[e] * SS + a[EE + e];
    float g = (br ? xg_out : xg_in)[srcn] + (br ? b_outg : b_ing)[l];
    u_sl[tid] = 1 + br * LL + l;
    u_src[tid] = srcn;
    u_w[tid] = sigm(g) * (br ? mask_out : mask_in)[e];
  }
  __syncthreads();

  const unsigned short* hp = (const unsigned short*)H;
  int d4 = tid * 4;
  float r0, r1, r2, r3;
  {
    float wl = sigm(xg_loop[n]) * mask_loop[n];
    ushort4 v = *(const ushort4*)&hp[(size_t)n * UU + d4];  // H[0][n]
    r0 = wl * bf2f(v.x); r1 = wl * bf2f(v.y);
    r2 = wl * bf2f(v.z); r3 = wl * bf2f(v.w);
  }
#pragma unroll
  for (int e = 0; e < 32; e++) {
    int sl = u_sl[e];
    int srcn = u_src[e];
    float w = u_w[e];
    ushort4 h = *(const ushort4*)&hp[((size_t)sl * NN + srcn) * UU + d4];
    const float* bp = (sl <= LL) ? b_in + (size_t)(sl - 1) * UU
                                 : b_out + (size_t)(sl - 1 - LL) * UU;
    float4 bv = *(const float4*)&bp[d4];
    r0 += w * (bf2f(h.x) + bv.x);
    r1 += w * (bf2f(h.y) + bv.y);
    r2 += w * (bf2f(h.z) + bv.z);
    r3 += w * (bf2f(h.w) + bv.w);
  }
  int s = n % SS, b = n / SS;
  float sm = sent[s * BB + b];
  float4 o;
  o.x = fmaxf(r0, 0.f) * sm; o.y = fmaxf(r1, 0.f) * sm;
  o.z = fmaxf(r2, 0.f) * sm; o.w = fmaxf(r3, 0.f) * sm;
  *(float4*)&out[((size_t)s * BB + b) * UU + d4] = o;
}

extern "C" void kernel_launch(void* const* d_in, const int* in_sizes, int n_in,
                              void* d_out, int out_size, void* d_ws, size_t ws_size,
                              hipStream_t stream) {
  const float* src      = (const float*)d_in[0];
  const float* V_in     = (const float*)d_in[1];
  const float* b_in     = (const float*)d_in[2];
  const float* V_ing    = (const float*)d_in[3];
  const float* b_ing    = (const float*)d_in[4];
  const float* V_out    = (const float*)d_in[5];
  const float* b_out    = (const float*)d_in[6];
  const float* V_outg   = (const float*)d_in[7];
  const float* b_outg   = (const float*)d_in[8];
  const float* W_self   = (const float*)d_in[9];
  const float* W_selfg  = (const float*)d_in[10];
  const int* arc_in     = (const int*)d_in[11];
  const int* arc_out    = (const int*)d_in[12];
  const int* lab_in     = (const int*)d_in[13];
  const int* lab_out    = (const int*)d_in[14];
  const float* mask_in  = (const float*)d_in[15];
  const float* mask_out = (const float*)d_in[16];
  const float* mask_loop= (const float*)d_in[17];
  const float* sent     = (const float*)d_in[18];
  float* out = (float*)d_out;

  char* ws = (char*)d_ws;
  size_t off = 0;
  auto alloc = [&](size_t bytes) -> void* {
    void* p = ws + off;
    off += (bytes + 255) & ~(size_t)255;
    return p;
  };
  __hip_bfloat16* x_bf = (__hip_bfloat16*)alloc((size_t)NN * DD * 2);          // 4 MB
  __hip_bfloat16* Vt   = (__hip_bfloat16*)alloc((size_t)NSLICE * UU * DD * 2); // 4.3 MB
  float* xg_in   = (float*)alloc(NN * 4);
  float* xg_out  = (float*)alloc(NN * 4);
  float* xg_loop = (float*)alloc(NN * 4);
  __hip_bfloat16* H = (__hip_bfloat16*)alloc((size_t)NSLICE * NN * UU * 2);    // 138 MB

  k_pre<<<NN + NSLICE * 64, 256, 0, stream>>>(
      src, V_ing, V_outg, W_selfg, V_in, V_out, W_self,
      x_bf, xg_in, xg_out, xg_loop, Vt);
  k_gemm<<<dim3(128, NSLICE), 256, 0, stream>>>(x_bf, Vt, H);
  k_agg<<<NN, 64, 0, stream>>>(H, xg_in, xg_out, xg_loop, b_in, b_out,
                               b_ing, b_outg, arc_in, arc_out, lab_in, lab_out,
                               mask_in, mask_out, mask_loop, sent, out);
}

// Round 13
// 168.393 us; speedup vs baseline: 1.1954x; 1.1954x over previous
//
#include <hip/hip_runtime.h>
#include <hip/hip_bf16.h>

// Problem constants (fixed by the reference).
#define BB 32
#define SS 256
#define DD 256
#define UU 256
#define LL 16
#define DEG 16
#define NN (BB * SS)   // 8192 nodes
#define EE (NN * DEG)  // 131072 edges per branch
#define NSLICE 33      // slice 0 = self-loop, 1..16 = in labels, 17..32 = out labels
#define TMR 128        // GEMM row tile
#define TNC 128        // GEMM col tile (U half)
#define BK 64          // GEMM k step
#define NTILES (DD / BK)  // 4 k-tiles (K = 256)
#define EST 136        // epilogue LDS row stride (elems); 64 rows/half-tile

using short8 = __attribute__((ext_vector_type(8))) short;  // 8 bf16 (4 VGPRs)
using f32x4  = __attribute__((ext_vector_type(4))) float;  // MFMA accumulator

// async global->LDS, 16B per lane, LDS dest = wave-uniform base + lane*16
#define GLDS(g, l)                                                        \
  __builtin_amdgcn_global_load_lds(                                       \
      (const __attribute__((address_space(1))) void*)(g),                 \
      (__attribute__((address_space(3))) void*)(l), 16, 0, 0)

__device__ __forceinline__ float bf2f(unsigned short v) {
  union { unsigned u; float f; } t;
  t.u = ((unsigned)v) << 16;
  return t.f;
}
__device__ __forceinline__ unsigned short f2bf(float f) {
  __hip_bfloat16 h = __float2bfloat16(f);
  return *(unsigned short*)&h;
}
__device__ __forceinline__ float sigm(float x) {
  return 1.f / (1.f + __expf(-x));
}

// ---------------------------------------------------------------------------
// K1: blocks [0,NN): prep (x cast to bf16 + 3 gate dots).
// blocks [NN, NN+NSLICE*64): weight transpose Vt[z][u][d] = V_z[d][u] (bf16).
// Verbatim R11 (passing). Bias applied per-edge in k_agg.
// ---------------------------------------------------------------------------
__global__ __launch_bounds__(256) void k_pre(
    const float* __restrict__ src, const float* __restrict__ gin,
    const float* __restrict__ gout, const float* __restrict__ gloop,
    const float* __restrict__ Vin, const float* __restrict__ Vout,
    const float* __restrict__ Wself,
    __hip_bfloat16* __restrict__ x_bf, float* __restrict__ xg_in,
    float* __restrict__ xg_out, float* __restrict__ xg_loop,
    __hip_bfloat16* __restrict__ Vt) {
  int bid = blockIdx.x;
  if (bid < NN) {
    int n = bid;
    int b = n / SS, s = n % SS;
    int d = threadIdx.x;
    float v = src[(size_t)(s * BB + b) * DD + d];
    x_bf[(size_t)n * DD + d] = __float2bfloat16(v);
    float p0 = v * gin[d], p1 = v * gout[d], p2 = v * gloop[d];
#pragma unroll
    for (int o = 32; o > 0; o >>= 1) {
      p0 += __shfl_down(p0, o);
      p1 += __shfl_down(p1, o);
      p2 += __shfl_down(p2, o);
    }
    __shared__ float r0[4], r1[4], r2[4];
    int w = threadIdx.x >> 6, lane = threadIdx.x & 63;
    if (lane == 0) { r0[w] = p0; r1[w] = p1; r2[w] = p2; }
    __syncthreads();
    if (threadIdx.x == 0) {
      xg_in[n]   = r0[0] + r0[1] + r0[2] + r0[3];
      xg_out[n]  = r1[0] + r1[1] + r1[2] + r1[3];
      xg_loop[n] = r2[0] + r2[1] + r2[2] + r2[3];
    }
    return;
  }
  int t = bid - NN;
  int z = t >> 6;                 // 0..NSLICE-1
  int rem = t & 63;
  int bx = rem & 7, by = rem >> 3;
  int tid = threadIdx.x;
  int tx = tid & 31, ty = tid >> 5;
  __shared__ float tbuf[32][33];
  const float* srcM = (z == 0) ? Wself
                    : (z <= LL ? Vin  + (size_t)(z - 1)      * DD * UU
                               : Vout + (size_t)(z - 1 - LL) * DD * UU);
  int u0 = bx * 32, d0 = by * 32;
#pragma unroll
  for (int i = 0; i < 4; i++) {
    int dr = ty + i * 8;
    tbuf[dr][tx] = srcM[(size_t)(d0 + dr) * UU + u0 + tx];
  }
  __syncthreads();
#pragma unroll
  for (int i = 0; i < 4; i++) {
    int ur = ty + i * 8;
    Vt[((size_t)z * UU + u0 + ur) * DD + d0 + tx] = __float2bfloat16(tbuf[tx][ur]);
  }
}

// ---------------------------------------------------------------------------
// K2: H[z] = x @ V_z, 128x128 tiles, 4 waves, single-buffered 32 KB LDS.
// R13 change vs R11: 3 -> 4 blocks/CU (launch_bounds(256,4): VGPR cap 128
// >= 68 so NO spill — R12's (256,5) capped VGPR at 48 < the 64 needed for
// acc alone and spilled to scratch: WRITE 135->231 MB, dur 50->79 us).
// Everything else verbatim R11 (T2 swizzle both sides, GLDS staging,
// unswapped C/D, LDS-transpose epilogue at EST=136).
// grid (128, 33): blockIdx.x = rowblk*2 + colhalf. 256 thr = 4 waves (2x2).
// ---------------------------------------------------------------------------
__global__ __launch_bounds__(256, 4) void k_gemm(
    const __hip_bfloat16* __restrict__ A, const __hip_bfloat16* __restrict__ Bt,
    __hip_bfloat16* __restrict__ H) {
  __shared__ __align__(16) __hip_bfloat16 smem[2 * TMR * BK];  // As | Bs, 32 KB

  const int tid = threadIdx.x;
  const int w = tid >> 6, lane = tid & 63;
  const int wm = w >> 1, wn = w & 1;           // wave grid 2x2
  const int lrow = lane & 15, quad = lane >> 4;

  const int z = blockIdx.y;
  const int bx = blockIdx.x >> 1;              // row block 0..63
  const int ch = blockIdx.x & 1;               // col half 0..1
  const int row0 = bx * TMR;
  const int col0 = ch * TNC;

  // Staging: round r covers rows [r*32, r*32+32); thread tid writes LDS
  // bytes r*4096 + tid*16 (linear dest). Global source pre-swizzled (T2):
  // chunk (tid&7) ^ (row&7); round rows are 32-aligned so key = arow&7.
  const int arow = tid >> 3;                       // 0..31 row within round
  const int scol = ((tid & 7) ^ (arow & 7)) << 3;  // swizzled k-elem offset
  const __hip_bfloat16* srcA = A + (size_t)(row0 + arow) * DD + scol;
  const __hip_bfloat16* srcB = Bt + ((size_t)z * UU + col0 + arow) * DD + scol;

  __hip_bfloat16* As = smem;
  __hip_bfloat16* Bs = smem + TMR * BK;

  // ds_read swizzled k-slot offsets (elements) for the two k-halves;
  // read rows are 16-aligned + lrow so key = lrow&7.
  const int sc0 = ((quad ^ (lrow & 7)) << 3);
  const int sc1 = (((4 + quad) ^ (lrow & 7)) << 3);

  f32x4 acc[4][4] = {};

  for (int t = 0; t < NTILES; ++t) {
    const int k0 = t * BK;
#pragma unroll
    for (int r = 0; r < 4; ++r)
      GLDS(srcA + (size_t)(r * 32) * DD + k0, &As[r * 2048 + (w << 9)]);
#pragma unroll
    for (int r = 0; r < 4; ++r)
      GLDS(srcB + (size_t)(r * 32) * DD + k0, &Bs[r * 2048 + (w << 9)]);
    __syncthreads();   // compiler emits vmcnt(0)+lgkmcnt(0) before barrier

    short8 af[4][2];
#pragma unroll
    for (int i = 0; i < 4; ++i) {
      int ro = (wm * 64 + i * 16 + lrow) * BK;
      af[i][0] = *(const short8*)&As[ro + sc0];
      af[i][1] = *(const short8*)&As[ro + sc1];
    }
#pragma unroll
    for (int j = 0; j < 4; ++j) {
      int ro = (wn * 64 + j * 16 + lrow) * BK;
      short8 b0 = *(const short8*)&Bs[ro + sc0];
      short8 b1 = *(const short8*)&Bs[ro + sc1];
#pragma unroll
      for (int i = 0; i < 4; ++i) {
        acc[i][j] = __builtin_amdgcn_mfma_f32_16x16x32_bf16(
            af[i][0], b0, acc[i][j], 0, 0, 0);
        acc[i][j] = __builtin_amdgcn_mfma_f32_16x16x32_bf16(
            af[i][1], b1, acc[i][j], 0, 0, 0);
      }
    }
    __syncthreads();   // reads done before next tile's staging overwrites
  }

  // ---- Epilogue: two 64-row half-tiles through LDS, coalesced stores ----
  // Wave wm owns tile rows [wm*64, wm*64+64) = half h == wm.
  unsigned short* ep = (unsigned short*)smem;     // needs 64*136=8704 elems
  unsigned short* hp = (unsigned short*)H;
#pragma unroll
  for (int h = 0; h < 2; ++h) {
    if (wm == h) {
      // unswapped C/D layout (R8/R10/R11-verified): col=lane&15 -> u,
      // quad*4+r -> n within the 16x16 fragment.
#pragma unroll
      for (int i = 0; i < 4; ++i)
#pragma unroll
        for (int j = 0; j < 4; ++j) {
          int col = wn * 64 + j * 16 + lrow;     // u in [0,128)
          int rowl = i * 16 + quad * 4;          // row within half [0,64)
#pragma unroll
          for (int r = 0; r < 4; ++r)
            ep[(rowl + r) * EST + col] = f2bf(acc[i][j][r]);
        }
    }
    __syncthreads();
    // 64 rows x 16 chunks of 16 B = 1024 chunks; 256 thr x 4 iters
#pragma unroll
    for (int it = 0; it < 4; ++it) {
      int idx = it * 256 + tid;
      int rr = idx >> 4;                 // 0..63
      int cc = (idx & 15) << 3;          // u chunk (elems)
      short8 v = *(const short8*)&ep[rr * EST + cc];
      *(short8*)&hp[((size_t)z * NN + row0 + h * 64 + rr) * UU + col0 + cc] = v;
    }
    __syncthreads();   // copy done before next half overwrites ep
  }
}

// ---------------------------------------------------------------------------
// K3: aggregation in U-space, fused with bias/relu/sent_mask/transpose.
// Verbatim R2/R10/R11 (passing). One wave per dst node; per-edge gather is
// a wave-uniform 512 B row of H.
// ---------------------------------------------------------------------------
__global__ __launch_bounds__(64) void k_agg(
    const __hip_bfloat16* __restrict__ H,
    const float* __restrict__ xg_in, const float* __restrict__ xg_out,
    const float* __restrict__ xg_loop,
    const float* __restrict__ b_in, const float* __restrict__ b_out,
    const float* __restrict__ b_ing, const float* __restrict__ b_outg,
    const int* __restrict__ arc_in, const int* __restrict__ arc_out,
    const int* __restrict__ lab_in, const int* __restrict__ lab_out,
    const float* __restrict__ mask_in, const float* __restrict__ mask_out,
    const float* __restrict__ mask_loop, const float* __restrict__ sent,
    float* __restrict__ out) {
  __shared__ int u_sl[32], u_src[32];
  __shared__ float u_w[32];
  int n = blockIdx.x, tid = threadIdx.x;
  if (tid < 32) {
    int br = tid >> 4, k = tid & 15;
    int e = n * DEG + k;
    const int* a = br ? arc_out : arc_in;
    int l = (br ? lab_out : lab_in)[e];
    int srcn = a[e] * SS + a[EE + e];
    float g = (br ? xg_out : xg_in)[srcn] + (br ? b_outg : b_ing)[l];
    u_sl[tid] = 1 + br * LL + l;
    u_src[tid] = srcn;
    u_w[tid] = sigm(g) * (br ? mask_out : mask_in)[e];
  }
  __syncthreads();

  const unsigned short* hp = (const unsigned short*)H;
  int d4 = tid * 4;
  float r0, r1, r2, r3;
  {
    float wl = sigm(xg_loop[n]) * mask_loop[n];
    ushort4 v = *(const ushort4*)&hp[(size_t)n * UU + d4];  // H[0][n]
    r0 = wl * bf2f(v.x); r1 = wl * bf2f(v.y);
    r2 = wl * bf2f(v.z); r3 = wl * bf2f(v.w);
  }
#pragma unroll
  for (int e = 0; e < 32; e++) {
    int sl = u_sl[e];
    int srcn = u_src[e];
    float w = u_w[e];
    ushort4 h = *(const ushort4*)&hp[((size_t)sl * NN + srcn) * UU + d4];
    const float* bp = (sl <= LL) ? b_in + (size_t)(sl - 1) * UU
                                 : b_out + (size_t)(sl - 1 - LL) * UU;
    float4 bv = *(const float4*)&bp[d4];
    r0 += w * (bf2f(h.x) + bv.x);
    r1 += w * (bf2f(h.y) + bv.y);
    r2 += w * (bf2f(h.z) + bv.z);
    r3 += w * (bf2f(h.w) + bv.w);
  }
  int s = n % SS, b = n / SS;
  float sm = sent[s * BB + b];
  float4 o;
  o.x = fmaxf(r0, 0.f) * sm; o.y = fmaxf(r1, 0.f) * sm;
  o.z = fmaxf(r2, 0.f) * sm; o.w = fmaxf(r3, 0.f) * sm;
  *(float4*)&out[((size_t)s * BB + b) * UU + d4] = o;
}

extern "C" void kernel_launch(void* const* d_in, const int* in_sizes, int n_in,
                              void* d_out, int out_size, void* d_ws, size_t ws_size,
                              hipStream_t stream) {
  const float* src      = (const float*)d_in[0];
  const float* V_in     = (const float*)d_in[1];
  const float* b_in     = (const float*)d_in[2];
  const float* V_ing    = (const float*)d_in[3];
  const float* b_ing    = (const float*)d_in[4];
  const float* V_out    = (const float*)d_in[5];
  const float* b_out    = (const float*)d_in[6];
  const float* V_outg   = (const float*)d_in[7];
  const float* b_outg   = (const float*)d_in[8];
  const float* W_self   = (const float*)d_in[9];
  const float* W_selfg  = (const float*)d_in[10];
  const int* arc_in     = (const int*)d_in[11];
  const int* arc_out    = (const int*)d_in[12];
  const int* lab_in     = (const int*)d_in[13];
  const int* lab_out    = (const int*)d_in[14];
  const float* mask_in  = (const float*)d_in[15];
  const float* mask_out = (const float*)d_in[16];
  const float* mask_loop= (const float*)d_in[17];
  const float* sent     = (const float*)d_in[18];
  float* out = (float*)d_out;

  char* ws = (char*)d_ws;
  size_t off = 0;
  auto alloc = [&](size_t bytes) -> void* {
    void* p = ws + off;
    off += (bytes + 255) & ~(size_t)255;
    return p;
  };
  __hip_bfloat16* x_bf = (__hip_bfloat16*)alloc((size_t)NN * DD * 2);          // 4 MB
  __hip_bfloat16* Vt   = (__hip_bfloat16*)alloc((size_t)NSLICE * UU * DD * 2); // 4.3 MB
  float* xg_in   = (float*)alloc(NN * 4);
  float* xg_out  = (float*)alloc(NN * 4);
  float* xg_loop = (float*)alloc(NN * 4);
  __hip_bfloat16* H = (__hip_bfloat16*)alloc((size_t)NSLICE * NN * UU * 2);    // 138 MB

  k_pre<<<NN + NSLICE * 64, 256, 0, stream>>>(
      src, V_ing, V_outg, W_selfg, V_in, V_out, W_self,
      x_bf, xg_in, xg_out, xg_loop, Vt);
  k_gemm<<<dim3(128, NSLICE), 256, 0, stream>>>(x_bf, Vt, H);
  k_agg<<<NN, 64, 0, stream>>>(H, xg_in, xg_out, xg_loop, b_in, b_out,
                               b_ing, b_outg, arc_in, arc_out, lab_in, lab_out,
                               mask_in, mask_out, mask_loop, sent, out);
}